// Round 2
// baseline (2055.855 us; speedup 1.0000x reference)
//
#include <hip/hip_runtime.h>
#include <hip/hip_bf16.h>

#define NPTS  40960
#define BATCH 4
#define BNPTS (NPTS * BATCH)   // 163840 points
#define KNB   16

typedef const float* __restrict__ fp32p;

__device__ __forceinline__ void stage(float* dst, const float* src, int n, int tid) {
    for (int i = tid; i < n; i += 256) dst[i] = src[i];
}

// ---------------------------------------------------------------- kernel 1: f_pc = cb(feature, mlp1)
struct S1 {
    alignas(16) float w[32 * 32];
    float s[32], b[32];
    alignas(16) float feat[8 * 32];
};

__global__ __launch_bounds__(256)
void k_mlp1(fp32p feature, fp32p w, fp32p s, fp32p b, float* __restrict__ f_pc) {
    __shared__ S1 sm;
    const int tid = threadIdx.x;
    stage(sm.w, w, 1024, tid);
    if (tid < 32) { sm.s[tid] = s[tid]; sm.b[tid] = b[tid]; }
    const int p0 = blockIdx.x * 8;
    sm.feat[tid] = feature[p0 * 32 + tid];   // 8 points x 32 ch, coalesced
    __syncthreads();
    const int lp = tid >> 5;     // local point 0..7
    const int co = tid & 31;     // out channel
    float acc = 0.f;
    #pragma unroll
    for (int i = 0; i < 32; i++) acc += sm.feat[lp * 32 + i] * sm.w[i * 32 + co];
    float y = acc * sm.s[co] + sm.b[co];
    f_pc[(p0 + lp) * 32 + co] = y > 0.f ? y : 0.f;
}

// ---------------------------------------------------------------- kernel 2: attention block 1 -> f_agg
struct S2 {
    alignas(16) float wfc[64 * 64];
    alignas(16) float wlfa[10 * 32];
    alignas(16) float wmlp[64 * 32];
    float slfa[32], blfa[32], smlp[32], bmlp[32];
    alignas(16) float fcat[4][16 * 64];
    alignas(16) float rp[4][16 * 10];
    alignas(16) float agg[4][64];
};

__global__ __launch_bounds__(256)
void k_att1(fp32p xyz, const int* __restrict__ nidx, const float* __restrict__ f_pc,
            fp32p wlfa, fp32p slfa, fp32p blfa, fp32p wfc,
            fp32p wmlp, fp32p smlp, fp32p bmlp,
            float* __restrict__ f_agg) {
    __shared__ S2 sm;
    const int tid = threadIdx.x;
    stage(sm.wfc, wfc, 4096, tid);
    stage(sm.wlfa, wlfa, 320, tid);
    stage(sm.wmlp, wmlp, 2048, tid);
    if (tid < 32) {
        sm.slfa[tid] = slfa[tid]; sm.blfa[tid] = blfa[tid];
        sm.smlp[tid] = smlp[tid]; sm.bmlp[tid] = bmlp[tid];
    }
    __syncthreads();
    const int w = tid >> 6, lane = tid & 63;
    float* fcat = sm.fcat[w];
    float* rp   = sm.rp[w];
    float* agg  = sm.agg[w];

    for (int it = 0; it < 4; it++) {
        const int p  = blockIdx.x * 16 + it * 4 + w;
        const int pb = (p / NPTS) * NPTS;

        // Phase A: rel_pos (lanes 0..15) + gather f_pc -> fcat[:, 0:32] (all lanes)
        if (lane < 16) {
            const int j = nidx[p * KNB + lane];
            const int r = (pb + j) * 3, c = p * 3;
            float cx = xyz[c], cy = xyz[c + 1], cz = xyz[c + 2];
            float nx = xyz[r], ny = xyz[r + 1], nz = xyz[r + 2];
            float rx = cx - nx, ry = cy - ny, rz = cz - nz;
            float d = sqrtf(rx * rx + ry * ry + rz * rz);
            float* q = rp + lane * 10;
            q[0] = d;  q[1] = rx; q[2] = ry; q[3] = rz;
            q[4] = cx; q[5] = cy; q[6] = cz; q[7] = nx; q[8] = ny; q[9] = nz;
        }
        {
            const int k = lane >> 2, part = lane & 3;
            const int j = nidx[p * KNB + k];
            const float* src = f_pc + (pb + j) * 32 + part * 8;
            float4 v0 = *(const float4*)src;
            float4 v1 = *(const float4*)(src + 4);
            *(float4*)(fcat + k * 64 + part * 8)     = v0;
            *(float4*)(fcat + k * 64 + part * 8 + 4) = v1;
        }
        __syncthreads();

        // Phase B: lfa1 -> fcat[:, 32:64]
        {
            const int c = lane & 31, kh = lane >> 5;
            const float sc = sm.slfa[c], bc = sm.blfa[c];
            #pragma unroll
            for (int kk = 0; kk < 8; kk++) {
                const int k = kh * 8 + kk;
                float acc = 0.f;
                #pragma unroll
                for (int i = 0; i < 10; i++) acc += rp[k * 10 + i] * sm.wlfa[i * 32 + c];
                float y = acc * sc + bc;
                fcat[k * 64 + 32 + c] = y > 0.f ? y : 0.f;
            }
        }
        __syncthreads();

        // Phase C: logits = fcat @ wfc, softmax over k per column, agg
        {
            float acc[16];
            #pragma unroll
            for (int k = 0; k < 16; k++) acc[k] = 0.f;
            #pragma unroll 4
            for (int c4 = 0; c4 < 16; c4++) {
                const float w0 = sm.wfc[(c4 * 4 + 0) * 64 + lane];
                const float w1 = sm.wfc[(c4 * 4 + 1) * 64 + lane];
                const float w2 = sm.wfc[(c4 * 4 + 2) * 64 + lane];
                const float w3 = sm.wfc[(c4 * 4 + 3) * 64 + lane];
                #pragma unroll
                for (int k = 0; k < 16; k++) {
                    const float4 f = *(const float4*)(fcat + k * 64 + c4 * 4);
                    acc[k] += f.x * w0; acc[k] += f.y * w1;
                    acc[k] += f.z * w2; acc[k] += f.w * w3;
                }
            }
            float m = acc[0];
            #pragma unroll
            for (int k = 1; k < 16; k++) m = fmaxf(m, acc[k]);
            float ssum = 0.f;
            #pragma unroll
            for (int k = 0; k < 16; k++) { acc[k] = __expf(acc[k] - m); ssum += acc[k]; }
            float a = 0.f;
            #pragma unroll
            for (int k = 0; k < 16; k++) a += fcat[k * 64 + lane] * acc[k];
            agg[lane] = a / ssum;
        }
        __syncthreads();

        // Phase D: f_agg = cb(agg, att1_mlp)
        if (lane < 32) {
            float acc = 0.f;
            #pragma unroll
            for (int d = 0; d < 64; d++) acc += agg[d] * sm.wmlp[d * 32 + lane];
            float y = acc * sm.smlp[lane] + sm.bmlp[lane];
            f_agg[p * 32 + lane] = y > 0.f ? y : 0.f;
        }
        __syncthreads();
    }
}

// ---------------------------------------------------------------- kernel 3: attention block 2 -> f_pc2
struct S3 {
    alignas(16) float wlfa1[10 * 32];
    alignas(16) float wlfa2[32 * 32];
    alignas(16) float wfc[64 * 64];
    alignas(16) float wmlp[64 * 64];
    float slfa1[32], blfa1[32], slfa2[32], blfa2[32], smlp[64], bmlp[64];
    alignas(16) float fcat[4][16 * 64];
    alignas(16) float rp[4][16 * 10];
    alignas(16) float agg[4][64];
};

__global__ __launch_bounds__(256)
void k_att2(fp32p xyz, const int* __restrict__ nidx, const float* __restrict__ f_agg,
            fp32p wlfa1, fp32p slfa1, fp32p blfa1,
            fp32p wlfa2, fp32p slfa2, fp32p blfa2,
            fp32p wfc, fp32p wmlp, fp32p smlp, fp32p bmlp,
            float* __restrict__ f_pc2) {
    __shared__ S3 sm;
    const int tid = threadIdx.x;
    stage(sm.wlfa1, wlfa1, 320, tid);
    stage(sm.wlfa2, wlfa2, 1024, tid);
    stage(sm.wfc, wfc, 4096, tid);
    stage(sm.wmlp, wmlp, 4096, tid);
    if (tid < 32) {
        sm.slfa1[tid] = slfa1[tid]; sm.blfa1[tid] = blfa1[tid];
        sm.slfa2[tid] = slfa2[tid]; sm.blfa2[tid] = blfa2[tid];
    }
    if (tid < 64) { sm.smlp[tid] = smlp[tid]; sm.bmlp[tid] = bmlp[tid]; }
    __syncthreads();
    const int w = tid >> 6, lane = tid & 63;
    float* fcat = sm.fcat[w];
    float* rp   = sm.rp[w];
    float* agg  = sm.agg[w];

    for (int it = 0; it < 4; it++) {
        const int p  = blockIdx.x * 16 + it * 4 + w;
        const int pb = (p / NPTS) * NPTS;

        // Phase A: rel_pos + gather f_agg -> fcat[:, 0:32]
        if (lane < 16) {
            const int j = nidx[p * KNB + lane];
            const int r = (pb + j) * 3, c = p * 3;
            float cx = xyz[c], cy = xyz[c + 1], cz = xyz[c + 2];
            float nx = xyz[r], ny = xyz[r + 1], nz = xyz[r + 2];
            float rx = cx - nx, ry = cy - ny, rz = cz - nz;
            float d = sqrtf(rx * rx + ry * ry + rz * rz);
            float* q = rp + lane * 10;
            q[0] = d;  q[1] = rx; q[2] = ry; q[3] = rz;
            q[4] = cx; q[5] = cy; q[6] = cz; q[7] = nx; q[8] = ny; q[9] = nz;
        }
        {
            const int k = lane >> 2, part = lane & 3;
            const int j = nidx[p * KNB + k];
            const float* src = f_agg + (pb + j) * 32 + part * 8;
            float4 v0 = *(const float4*)src;
            float4 v1 = *(const float4*)(src + 4);
            *(float4*)(fcat + k * 64 + part * 8)     = v0;
            *(float4*)(fcat + k * 64 + part * 8 + 4) = v1;
        }
        __syncthreads();

        // Phase B: lfa1 (recompute f_xyz) -> fcat[:, 32:64] (temporary)
        {
            const int c = lane & 31, kh = lane >> 5;
            const float sc = sm.slfa1[c], bc = sm.blfa1[c];
            #pragma unroll
            for (int kk = 0; kk < 8; kk++) {
                const int k = kh * 8 + kk;
                float acc = 0.f;
                #pragma unroll
                for (int i = 0; i < 10; i++) acc += rp[k * 10 + i] * sm.wlfa1[i * 32 + c];
                float y = acc * sc + bc;
                fcat[k * 64 + 32 + c] = y > 0.f ? y : 0.f;
            }
        }
        __syncthreads();

        // Phase B2: lfa2 in-place over fcat[:, 32:64] via registers
        float fx2[8];
        {
            const int c = lane & 31, kh = lane >> 5;
            const float sc = sm.slfa2[c], bc = sm.blfa2[c];
            #pragma unroll
            for (int kk = 0; kk < 8; kk++) {
                const int k = kh * 8 + kk;
                float acc = 0.f;
                #pragma unroll
                for (int i = 0; i < 32; i++) acc += fcat[k * 64 + 32 + i] * sm.wlfa2[i * 32 + c];
                float y = acc * sc + bc;
                fx2[kk] = y > 0.f ? y : 0.f;
            }
        }
        __syncthreads();
        {
            const int c = lane & 31, kh = lane >> 5;
            #pragma unroll
            for (int kk = 0; kk < 8; kk++) fcat[(kh * 8 + kk) * 64 + 32 + c] = fx2[kk];
        }
        __syncthreads();

        // Phase C: logits, softmax over k, agg
        {
            float acc[16];
            #pragma unroll
            for (int k = 0; k < 16; k++) acc[k] = 0.f;
            #pragma unroll 4
            for (int c4 = 0; c4 < 16; c4++) {
                const float w0 = sm.wfc[(c4 * 4 + 0) * 64 + lane];
                const float w1 = sm.wfc[(c4 * 4 + 1) * 64 + lane];
                const float w2 = sm.wfc[(c4 * 4 + 2) * 64 + lane];
                const float w3 = sm.wfc[(c4 * 4 + 3) * 64 + lane];
                #pragma unroll
                for (int k = 0; k < 16; k++) {
                    const float4 f = *(const float4*)(fcat + k * 64 + c4 * 4);
                    acc[k] += f.x * w0; acc[k] += f.y * w1;
                    acc[k] += f.z * w2; acc[k] += f.w * w3;
                }
            }
            float m = acc[0];
            #pragma unroll
            for (int k = 1; k < 16; k++) m = fmaxf(m, acc[k]);
            float ssum = 0.f;
            #pragma unroll
            for (int k = 0; k < 16; k++) { acc[k] = __expf(acc[k] - m); ssum += acc[k]; }
            float a = 0.f;
            #pragma unroll
            for (int k = 0; k < 16; k++) a += fcat[k * 64 + lane] * acc[k];
            agg[lane] = a / ssum;
        }
        __syncthreads();

        // Phase D: f_pc2 = cb(agg, att2_mlp)  (64 outputs, all lanes)
        {
            float acc = 0.f;
            #pragma unroll
            for (int c = 0; c < 64; c++) acc += agg[c] * sm.wmlp[c * 64 + lane];
            float y = acc * sm.smlp[lane] + sm.bmlp[lane];
            f_pc2[p * 64 + lane] = y > 0.f ? y : 0.f;
        }
        __syncthreads();
    }
}

// ---------------------------------------------------------------- kernel 4: out = leaky(cb(f_pc2,mlp2) + cb(feature,sc))
struct S4 {
    alignas(16) float w2[64 * 128];
    alignas(16) float wsc[32 * 128];
    float s2[128], ssc[128], bc[128];
    alignas(16) float pc2[4][64];
    alignas(16) float feat[4][32];
};

__global__ __launch_bounds__(256)
void k_out(const float* __restrict__ f_pc2, fp32p feature,
           fp32p w2, fp32p s2, fp32p b2, fp32p wsc, fp32p ssc, fp32p bsc,
           float* __restrict__ out) {
    __shared__ S4 sm;
    const int tid = threadIdx.x;
    stage(sm.w2, w2, 8192, tid);
    stage(sm.wsc, wsc, 4096, tid);
    if (tid < 128) {
        sm.s2[tid]  = s2[tid];
        sm.ssc[tid] = ssc[tid];
        sm.bc[tid]  = b2[tid] + bsc[tid];   // folded bias
    }
    __syncthreads();
    const int w = tid >> 6, lane = tid & 63;

    for (int it = 0; it < 4; it++) {
        const int p = blockIdx.x * 16 + it * 4 + w;
        sm.pc2[w][lane] = f_pc2[p * 64 + lane];
        if (lane < 32) sm.feat[w][lane] = feature[p * 32 + lane];
        __syncthreads();
        const float* pc2 = sm.pc2[w];
        const float* ft  = sm.feat[w];
        const int d0 = lane, d1 = lane + 64;
        float a0 = 0.f, a1 = 0.f;
        #pragma unroll 8
        for (int c = 0; c < 64; c++) {
            const float v = pc2[c];
            a0 += v * sm.w2[c * 128 + d0];
            a1 += v * sm.w2[c * 128 + d1];
        }
        float s0 = 0.f, s1 = 0.f;
        #pragma unroll 8
        for (int i = 0; i < 32; i++) {
            const float v = ft[i];
            s0 += v * sm.wsc[i * 128 + d0];
            s1 += v * sm.wsc[i * 128 + d1];
        }
        float y0 = a0 * sm.s2[d0] + s0 * sm.ssc[d0] + sm.bc[d0];
        float y1 = a1 * sm.s2[d1] + s1 * sm.ssc[d1] + sm.bc[d1];
        y0 = y0 > 0.f ? y0 : 0.2f * y0;
        y1 = y1 > 0.f ? y1 : 0.2f * y1;
        out[p * 128 + d0] = y0;
        out[p * 128 + d1] = y1;
        __syncthreads();
    }
}

// ---------------------------------------------------------------- launch
extern "C" void kernel_launch(void* const* d_in, const int* in_sizes, int n_in,
                              void* d_out, int out_size, void* d_ws, size_t ws_size,
                              hipStream_t stream) {
    const float* feature = (const float*)d_in[0];
    const float* xyz     = (const float*)d_in[1];
    const int*   nidx    = (const int*)d_in[2];
    const float* w_mlp1 = (const float*)d_in[3];
    const float* s_mlp1 = (const float*)d_in[4];
    const float* b_mlp1 = (const float*)d_in[5];
    const float* w_lfa1 = (const float*)d_in[6];
    const float* s_lfa1 = (const float*)d_in[7];
    const float* b_lfa1 = (const float*)d_in[8];
    const float* w_att1_fc  = (const float*)d_in[9];
    const float* w_att1_mlp = (const float*)d_in[10];
    const float* s_att1_mlp = (const float*)d_in[11];
    const float* b_att1_mlp = (const float*)d_in[12];
    const float* w_lfa2 = (const float*)d_in[13];
    const float* s_lfa2 = (const float*)d_in[14];
    const float* b_lfa2 = (const float*)d_in[15];
    const float* w_att2_fc  = (const float*)d_in[16];
    const float* w_att2_mlp = (const float*)d_in[17];
    const float* s_att2_mlp = (const float*)d_in[18];
    const float* b_att2_mlp = (const float*)d_in[19];
    const float* w_mlp2 = (const float*)d_in[20];
    const float* s_mlp2 = (const float*)d_in[21];
    const float* b_mlp2 = (const float*)d_in[22];
    const float* w_sc = (const float*)d_in[23];
    const float* s_sc = (const float*)d_in[24];
    const float* b_sc = (const float*)d_in[25];

    float* f_pc  = (float*)d_ws;                      // BNPTS*32
    float* f_agg = f_pc  + (size_t)BNPTS * 32;        // BNPTS*32
    float* f_pc2 = f_agg + (size_t)BNPTS * 32;        // BNPTS*64  (84 MB total)
    float* out = (float*)d_out;

    k_mlp1<<<BNPTS / 8, 256, 0, stream>>>(feature, w_mlp1, s_mlp1, b_mlp1, f_pc);
    k_att1<<<BNPTS / 16, 256, 0, stream>>>(xyz, nidx, f_pc,
                                           w_lfa1, s_lfa1, b_lfa1, w_att1_fc,
                                           w_att1_mlp, s_att1_mlp, b_att1_mlp, f_agg);
    k_att2<<<BNPTS / 16, 256, 0, stream>>>(xyz, nidx, f_agg,
                                           w_lfa1, s_lfa1, b_lfa1,
                                           w_lfa2, s_lfa2, b_lfa2,
                                           w_att2_fc, w_att2_mlp, s_att2_mlp, b_att2_mlp, f_pc2);
    k_out<<<BNPTS / 16, 256, 0, stream>>>(f_pc2, feature,
                                          w_mlp2, s_mlp2, b_mlp2,
                                          w_sc, s_sc, b_sc, out);
}

// Round 3
// 582.673 us; speedup vs baseline: 3.5283x; 3.5283x over previous
//
#include <hip/hip_runtime.h>
#include <hip/hip_bf16.h>

#define NPTS  40960
#define BNPTS 163840   // 4 batches x 40960
#define KNB   16

using bf16x8 = __attribute__((ext_vector_type(8))) short;
using f32x4  = __attribute__((ext_vector_type(4))) float;

__device__ __forceinline__ unsigned short f2bf(float x) {
    union { float f; unsigned u; } v; v.f = x;
    unsigned r = v.u + 0x7fffu + ((v.u >> 16) & 1u);   // RTNE
    return (unsigned short)(r >> 16);
}
__device__ __forceinline__ float bf2f(unsigned short u) {
    union { unsigned u; float f; } v; v.u = ((unsigned)u) << 16;
    return v.f;
}
__device__ __forceinline__ bf16x8 pack8(float a0, float a1, float a2, float a3,
                                        float a4, float a5, float a6, float a7) {
    union { unsigned short s[8]; bf16x8 v; } u;
    u.s[0] = f2bf(a0); u.s[1] = f2bf(a1); u.s[2] = f2bf(a2); u.s[3] = f2bf(a3);
    u.s[4] = f2bf(a4); u.s[5] = f2bf(a5); u.s[6] = f2bf(a6); u.s[7] = f2bf(a7);
    return u.v;
}
__device__ __forceinline__ f32x4 mfma16(bf16x8 a, bf16x8 b, f32x4 c) {
    return __builtin_amdgcn_mfma_f32_16x16x32_bf16(a, b, c, 0, 0, 0);
}

// ---------------------------------------------------------------- kernel 1: f_pc = cb(feature, mlp1) -> bf16 [pts][32]
__global__ __launch_bounds__(256)
void k_mlp1(const float* __restrict__ feature, const float* __restrict__ w,
            const float* __restrict__ s, const float* __restrict__ b,
            unsigned short* __restrict__ f_pc)
{
    __shared__ unsigned short wT[32 * 40];   // wT[d][c] = w[c][d], rows padded to 40 bf16
    __shared__ float sS[32], sB[32];
    const int tid = threadIdx.x;
    for (int t = tid; t < 1024; t += 256) {
        int c = t >> 5, d = t & 31;
        wT[d * 40 + c] = f2bf(w[t]);
    }
    if (tid < 32) { sS[tid] = s[tid]; sB[tid] = b[tid]; }
    __syncthreads();
    const int lid = tid & 63, wv = tid >> 6;
    const int col = lid & 15, quad = lid >> 4;
    bf16x8 B0 = *(const bf16x8*)&wT[col * 40 + quad * 8];
    bf16x8 B1 = *(const bf16x8*)&wT[(16 + col) * 40 + quad * 8];
    float s0 = sS[col], b0 = sB[col], s1 = sS[16 + col], b1 = sB[16 + col];
    for (int itp = 0; itp < 4; itp++) {
        const int p0 = blockIdx.x * 256 + wv * 64 + itp * 16;
        const float* fr = &feature[(size_t)(p0 + col) * 32 + quad * 8];
        float4 u0 = *(const float4*)fr;
        float4 u1 = *(const float4*)(fr + 4);
        bf16x8 a = pack8(u0.x, u0.y, u0.z, u0.w, u1.x, u1.y, u1.z, u1.w);
        f32x4 z = {0.f, 0.f, 0.f, 0.f};
        f32x4 d0 = mfma16(a, B0, z);
        f32x4 d1 = mfma16(a, B1, z);
        #pragma unroll
        for (int r = 0; r < 4; r++) {
            int p = p0 + quad * 4 + r;                     // C row = pt
            f_pc[(size_t)p * 32 + col]      = f2bf(fmaxf(d0[r] * s0 + b0, 0.f));
            f_pc[(size_t)p * 32 + 16 + col] = f2bf(fmaxf(d1[r] * s1 + b1, 0.f));
        }
    }
}

// ---------------------------------------------------------------- attention kernels (shared template)
// Per wave: 4 points/iter, wave-private LDS tiles, no block barriers in loop.
// fcat[pt][16 nbr][72 pad] bf16: cols 0:32 gathered src rows, cols 32:64 f_xyz (lfa1 [, then lfa2]).
template<int NOUT, bool HAS_LFA2>
__global__ __launch_bounds__(256)
void k_att(const float* __restrict__ xyz, const int* __restrict__ nidx,
           const unsigned short* __restrict__ src,
           const float* __restrict__ wlfa1, const float* __restrict__ slfa1, const float* __restrict__ blfa1,
           const float* __restrict__ wlfa2, const float* __restrict__ slfa2, const float* __restrict__ blfa2,
           const float* __restrict__ wfc,
           const float* __restrict__ wmlp, const float* __restrict__ smlp, const float* __restrict__ bmlp,
           unsigned short* __restrict__ out)
{
    constexpr int NT = NOUT / 16;
    __shared__ unsigned short wfcT[64 * 72];
    __shared__ unsigned short wl1T[32 * 40];
    __shared__ unsigned short wl2T[32 * 40];
    __shared__ unsigned short wmT[NOUT * 72];
    __shared__ float sl1[32], bl1[32], sl2[32], bl2[32], sml[NOUT], bml[NOUT];
    __shared__ unsigned short fcat[4][4 * 16 * 72];   // [wave][pt*1152 + nbr*72 + c]
    __shared__ unsigned short aggL[4][4 * 72];        // [wave][pt*72 + c]

    const int tid = threadIdx.x;
    // ---- stage weights (bf16, transposed to [out_ch][in_ch] for B-fragments)
    for (int t = tid; t < 64 * 64; t += 256) {
        int c = t >> 6, d = t & 63;
        wfcT[d * 72 + c] = f2bf(wfc[t]);
    }
    for (int t = tid; t < 32 * 32; t += 256) {
        int c = t >> 5, d = t & 31;
        wl1T[d * 40 + c] = f2bf(c < 10 ? wlfa1[c * 32 + d] : 0.f);  // zero K-pad rows (avoid 0*NaN)
        if (HAS_LFA2) wl2T[d * 40 + c] = f2bf(wlfa2[t]);
    }
    for (int t = tid; t < 64 * NOUT; t += 256) {
        int c = t / NOUT, d = t % NOUT;
        wmT[d * 72 + c] = f2bf(wmlp[t]);
    }
    if (tid < 32) {
        sl1[tid] = slfa1[tid]; bl1[tid] = blfa1[tid];
        if (HAS_LFA2) { sl2[tid] = slfa2[tid]; bl2[tid] = blfa2[tid]; }
    }
    if (tid < NOUT) { sml[tid] = smlp[tid]; bml[tid] = bmlp[tid]; }
    __syncthreads();

    const int lid = tid & 63, wv = tid >> 6;
    const int col = lid & 15, quad = lid >> 4;

    // ---- preload all B-fragments into registers (B[k][n]: n=lane&15, k=quad*8+j)
    bf16x8 Bfc[4][2];
    #pragma unroll
    for (int nt = 0; nt < 4; nt++)
        #pragma unroll
        for (int ks = 0; ks < 2; ks++)
            Bfc[nt][ks] = *(const bf16x8*)&wfcT[(nt * 16 + col) * 72 + ks * 32 + quad * 8];
    bf16x8 Bl1[2], Bl2[2];
    #pragma unroll
    for (int nt = 0; nt < 2; nt++) {
        Bl1[nt] = *(const bf16x8*)&wl1T[(nt * 16 + col) * 40 + quad * 8];
        if (HAS_LFA2) Bl2[nt] = *(const bf16x8*)&wl2T[(nt * 16 + col) * 40 + quad * 8];
    }
    bf16x8 Bm[NT][2];
    #pragma unroll
    for (int nt = 0; nt < NT; nt++)
        #pragma unroll
        for (int ks = 0; ks < 2; ks++)
            Bm[nt][ks] = *(const bf16x8*)&wmT[(nt * 16 + col) * 72 + ks * 32 + quad * 8];

    // hoisted per-lane scale/bias
    float sl1a = sl1[col], bl1a = bl1[col], sl1b = sl1[16 + col], bl1b = bl1[16 + col];
    float sl2a = 0.f, bl2a = 0.f, sl2b = 0.f, bl2b = 0.f;
    if (HAS_LFA2) { sl2a = sl2[col]; bl2a = bl2[col]; sl2b = sl2[16 + col]; bl2b = bl2[16 + col]; }
    float sm_[NT], bm_[NT];
    #pragma unroll
    for (int nt = 0; nt < NT; nt++) { sm_[nt] = sml[nt * 16 + col]; bm_[nt] = bml[nt * 16 + col]; }

    unsigned short* fc = fcat[wv];
    unsigned short* ag = aggL[wv];
    const f32x4 z = {0.f, 0.f, 0.f, 0.f};

    for (int it = 0; it < 4; it++) {
        const int p0 = blockIdx.x * 64 + wv * 16 + it * 4;   // this wave's 4 points
        const int pb = (p0 / NPTS) * NPTS;                   // batch base (block never straddles)

        // ---- gather neighbor features -> fcat[:, 0:32]   (lane = 16 nbr x 4 chunks of 8 bf16)
        {
            const int gk = lid >> 2, gp = lid & 3;
            #pragma unroll
            for (int pt = 0; pt < 4; pt++) {
                int j = nidx[(p0 + pt) * KNB + gk];
                bf16x8 v = *(const bf16x8*)&src[(size_t)(pb + j) * 32 + gp * 8];
                *(bf16x8*)&fc[pt * 1152 + gk * 72 + gp * 8] = v;
            }
        }

        // ---- lfa1 (A built in registers: row=nbr, cols=rel_pos features padded to 32) [+ lfa2]
        #pragma unroll 1
        for (int pt = 0; pt < 4; pt++) {
            const int p = p0 + pt;
            float f0 = 0.f, f1 = 0.f, f2 = 0.f, f3 = 0.f, f4 = 0.f, f5 = 0.f, f6 = 0.f, f7 = 0.f;
            if (quad < 2) {
                int j = nidx[p * KNB + col];
                float cx = xyz[p * 3], cy = xyz[p * 3 + 1], cz = xyz[p * 3 + 2];
                float nx = xyz[(pb + j) * 3], ny = xyz[(pb + j) * 3 + 1], nz = xyz[(pb + j) * 3 + 2];
                float rx = cx - nx, ry = cy - ny, rz = cz - nz;
                float dd = sqrtf(rx * rx + ry * ry + rz * rz);
                if (quad == 0) { f0 = dd; f1 = rx; f2 = ry; f3 = rz; f4 = cx; f5 = cy; f6 = cz; f7 = nx; }
                else           { f0 = ny; f1 = nz; }
            }
            bf16x8 a = pack8(f0, f1, f2, f3, f4, f5, f6, f7);
            f32x4 d0 = mfma16(a, Bl1[0], z);
            f32x4 d1 = mfma16(a, Bl1[1], z);
            #pragma unroll
            for (int r = 0; r < 4; r++) {
                int row = quad * 4 + r;
                fc[pt * 1152 + row * 72 + 32 + col] = f2bf(fmaxf(d0[r] * sl1a + bl1a, 0.f));
                fc[pt * 1152 + row * 72 + 48 + col] = f2bf(fmaxf(d1[r] * sl1b + bl1b, 0.f));
            }
            if (HAS_LFA2) {
                // A = f_xyz (rows=nbr, K=32) read back from fcat; overwrite with lfa2 output
                bf16x8 a2 = *(const bf16x8*)&fc[pt * 1152 + col * 72 + 32 + quad * 8];
                f32x4 e0 = mfma16(a2, Bl2[0], z);
                f32x4 e1 = mfma16(a2, Bl2[1], z);
                #pragma unroll
                for (int r = 0; r < 4; r++) {
                    int row = quad * 4 + r;
                    fc[pt * 1152 + row * 72 + 32 + col] = f2bf(fmaxf(e0[r] * sl2a + bl2a, 0.f));
                    fc[pt * 1152 + row * 72 + 48 + col] = f2bf(fmaxf(e1[r] * sl2b + bl2b, 0.f));
                }
            }
        }

        // ---- attention: logits GEMM + softmax over 16 nbr + pooled agg (per point)
        #pragma unroll 1
        for (int pt = 0; pt < 4; pt++) {
            bf16x8 a0 = *(const bf16x8*)&fc[pt * 1152 + col * 72 + quad * 8];        // rows=nbr, K 0:32
            bf16x8 a1 = *(const bf16x8*)&fc[pt * 1152 + col * 72 + 32 + quad * 8];   // K 32:64
            #pragma unroll
            for (int nt = 0; nt < 4; nt++) {
                f32x4 L = mfma16(a1, Bfc[nt][1], mfma16(a0, Bfc[nt][0], z));
                // C-layout: lane holds rows quad*4+r, col nt*16+(lane&15). Softmax over rows.
                float m = fmaxf(fmaxf(L[0], L[1]), fmaxf(L[2], L[3]));
                m = fmaxf(m, __shfl_xor(m, 16, 64));
                m = fmaxf(m, __shfl_xor(m, 32, 64));
                float e0 = __expf(L[0] - m), e1 = __expf(L[1] - m);
                float e2 = __expf(L[2] - m), e3 = __expf(L[3] - m);
                float sden = e0 + e1 + e2 + e3;
                sden += __shfl_xor(sden, 16, 64);
                sden += __shfl_xor(sden, 32, 64);
                const unsigned short* frr = &fc[pt * 1152 + quad * 4 * 72 + nt * 16 + col];
                float av = e0 * bf2f(frr[0]) + e1 * bf2f(frr[72]) + e2 * bf2f(frr[144]) + e3 * bf2f(frr[216]);
                av += __shfl_xor(av, 16, 64);
                av += __shfl_xor(av, 32, 64);
                av /= sden;
                if (quad == 0) ag[pt * 72 + nt * 16 + col] = f2bf(av);
            }
        }

        // ---- att-MLP batched over the 4 points (M-tile rows 0..3 real)
        {
            bf16x8 am0 = *(const bf16x8*)&ag[(col & 3) * 72 + quad * 8];
            bf16x8 am1 = *(const bf16x8*)&ag[(col & 3) * 72 + 32 + quad * 8];
            #pragma unroll
            for (int nt = 0; nt < NT; nt++) {
                f32x4 d = mfma16(am1, Bm[nt][1], mfma16(am0, Bm[nt][0], z));
                if (quad == 0) {   // rows 0..3 = the 4 points
                    #pragma unroll
                    for (int r = 0; r < 4; r++) {
                        float y = fmaxf(d[r] * sm_[nt] + bm_[nt], 0.f);
                        out[(size_t)(p0 + r) * NOUT + nt * 16 + col] = f2bf(y);
                    }
                }
            }
        }
    }
}

// ---------------------------------------------------------------- kernel 4: out = leaky(cb(f_pc2,mlp2) + cb(feature,sc))
__global__ __launch_bounds__(256)
void k_out(const unsigned short* __restrict__ f_pc2, const float* __restrict__ feature,
           const float* __restrict__ w2, const float* __restrict__ s2, const float* __restrict__ b2,
           const float* __restrict__ wsc, const float* __restrict__ ssc, const float* __restrict__ bsc,
           float* __restrict__ out)
{
    __shared__ unsigned short w2T[128 * 72];
    __shared__ unsigned short wsT[128 * 40];
    __shared__ float sA[128], sB2[128], sC[128];
    const int tid = threadIdx.x;
    for (int t = tid; t < 64 * 128; t += 256) {
        int c = t >> 7, d = t & 127;
        w2T[d * 72 + c] = f2bf(w2[t]);
    }
    for (int t = tid; t < 32 * 128; t += 256) {
        int c = t >> 7, d = t & 127;
        wsT[d * 40 + c] = f2bf(wsc[t]);
    }
    if (tid < 128) { sA[tid] = s2[tid]; sB2[tid] = ssc[tid]; sC[tid] = b2[tid] + bsc[tid]; }
    __syncthreads();
    const int lid = tid & 63, wv = tid >> 6;
    const int col = lid & 15, quad = lid >> 4;
    const f32x4 z = {0.f, 0.f, 0.f, 0.f};
    for (int itp = 0; itp < 2; itp++) {
        const int p0 = blockIdx.x * 128 + wv * 32 + itp * 16;
        const unsigned short* ar = &f_pc2[(size_t)(p0 + col) * 64 + quad * 8];
        bf16x8 a10 = *(const bf16x8*)ar;
        bf16x8 a11 = *(const bf16x8*)(ar + 32);
        const float* fr = &feature[(size_t)(p0 + col) * 32 + quad * 8];
        float4 u0 = *(const float4*)fr;
        float4 u1 = *(const float4*)(fr + 4);
        bf16x8 a2 = pack8(u0.x, u0.y, u0.z, u0.w, u1.x, u1.y, u1.z, u1.w);
        #pragma unroll
        for (int nt = 0; nt < 8; nt++) {
            bf16x8 bk0 = *(const bf16x8*)&w2T[(nt * 16 + col) * 72 + quad * 8];
            bf16x8 bk1 = *(const bf16x8*)&w2T[(nt * 16 + col) * 72 + 32 + quad * 8];
            bf16x8 bs  = *(const bf16x8*)&wsT[(nt * 16 + col) * 40 + quad * 8];
            f32x4 d = mfma16(a11, bk1, mfma16(a10, bk0, z));
            f32x4 e = mfma16(a2, bs, z);
            int n = nt * 16 + col;
            float ss = sA[n], st = sB2[n], bb = sC[n];
            #pragma unroll
            for (int r = 0; r < 4; r++) {
                float y = d[r] * ss + e[r] * st + bb;
                y = y > 0.f ? y : 0.2f * y;
                out[(size_t)(p0 + quad * 4 + r) * 128 + n] = y;
            }
        }
    }
}

// ---------------------------------------------------------------- launch
extern "C" void kernel_launch(void* const* d_in, const int* in_sizes, int n_in,
                              void* d_out, int out_size, void* d_ws, size_t ws_size,
                              hipStream_t stream) {
    const float* feature = (const float*)d_in[0];
    const float* xyz     = (const float*)d_in[1];
    const int*   nidx    = (const int*)d_in[2];
    const float* w_mlp1 = (const float*)d_in[3];
    const float* s_mlp1 = (const float*)d_in[4];
    const float* b_mlp1 = (const float*)d_in[5];
    const float* w_lfa1 = (const float*)d_in[6];
    const float* s_lfa1 = (const float*)d_in[7];
    const float* b_lfa1 = (const float*)d_in[8];
    const float* w_att1_fc  = (const float*)d_in[9];
    const float* w_att1_mlp = (const float*)d_in[10];
    const float* s_att1_mlp = (const float*)d_in[11];
    const float* b_att1_mlp = (const float*)d_in[12];
    const float* w_lfa2 = (const float*)d_in[13];
    const float* s_lfa2 = (const float*)d_in[14];
    const float* b_lfa2 = (const float*)d_in[15];
    const float* w_att2_fc  = (const float*)d_in[16];
    const float* w_att2_mlp = (const float*)d_in[17];
    const float* s_att2_mlp = (const float*)d_in[18];
    const float* b_att2_mlp = (const float*)d_in[19];
    const float* w_mlp2 = (const float*)d_in[20];
    const float* s_mlp2 = (const float*)d_in[21];
    const float* b_mlp2 = (const float*)d_in[22];
    const float* w_sc = (const float*)d_in[23];
    const float* s_sc = (const float*)d_in[24];
    const float* b_sc = (const float*)d_in[25];

    unsigned short* f_pc  = (unsigned short*)d_ws;               // [BNPTS][32] bf16
    unsigned short* f_agg = f_pc  + (size_t)BNPTS * 32;          // [BNPTS][32] bf16
    unsigned short* f_pc2 = f_agg + (size_t)BNPTS * 32;          // [BNPTS][64] bf16 (42 MB total)
    float* out = (float*)d_out;

    k_mlp1<<<BNPTS / 256, 256, 0, stream>>>(feature, w_mlp1, s_mlp1, b_mlp1, f_pc);
    k_att<32, false><<<BNPTS / 64, 256, 0, stream>>>(
        xyz, nidx, f_pc,
        w_lfa1, s_lfa1, b_lfa1,
        w_lfa1, s_lfa1, b_lfa1,              // lfa2 slots unused
        w_att1_fc, w_att1_mlp, s_att1_mlp, b_att1_mlp, f_agg);
    k_att<64, true><<<BNPTS / 64, 256, 0, stream>>>(
        xyz, nidx, f_agg,
        w_lfa1, s_lfa1, b_lfa1,
        w_lfa2, s_lfa2, b_lfa2,
        w_att2_fc, w_att2_mlp, s_att2_mlp, b_att2_mlp, f_pc2);
    k_out<<<BNPTS / 128, 256, 0, stream>>>(
        f_pc2, feature,
        w_mlp2, s_mlp2, b_mlp2,
        w_sc, s_sc, b_sc, out);
}

// Round 4
// 455.439 us; speedup vs baseline: 4.5140x; 1.2794x over previous
//
#include <hip/hip_runtime.h>
#include <hip/hip_bf16.h>

#define NPTS  40960
#define BNPTS 163840   // 4 batches x 40960
#define KNB   16

using bf16x8 = __attribute__((ext_vector_type(8))) short;
using f32x4  = __attribute__((ext_vector_type(4))) float;

__device__ __forceinline__ unsigned short f2bf(float x) {
    union { float f; unsigned u; } v; v.f = x;
    unsigned r = v.u + 0x7fffu + ((v.u >> 16) & 1u);   // RTNE
    return (unsigned short)(r >> 16);
}
__device__ __forceinline__ float bf2f(unsigned short u) {
    union { unsigned u; float f; } v; v.u = ((unsigned)u) << 16;
    return v.f;
}
// pack two floats -> packed bf16x2 (lo at low half) via v_cvt_pk_bf16_f32
__device__ __forceinline__ unsigned pk2(float lo, float hi) {
    union { __hip_bfloat162 h; unsigned u; } v;
    v.h = __float22bfloat162_rn(float2{lo, hi});
    return v.u;
}
__device__ __forceinline__ bf16x8 pack8(float a0, float a1, float a2, float a3,
                                        float a4, float a5, float a6, float a7) {
    union { unsigned u[4]; bf16x8 v; } w;
    w.u[0] = pk2(a0, a1); w.u[1] = pk2(a2, a3);
    w.u[2] = pk2(a4, a5); w.u[3] = pk2(a6, a7);
    return w.v;
}
__device__ __forceinline__ f32x4 mfma16(bf16x8 a, bf16x8 b, f32x4 c) {
    return __builtin_amdgcn_mfma_f32_16x16x32_bf16(a, b, c, 0, 0, 0);
}

// ---------------------------------------------------------------- kernel 1: f_pc = cb(feature, mlp1) -> bf16 [pts][32]
__global__ __launch_bounds__(256)
void k_mlp1(const float* __restrict__ feature, const float* __restrict__ w,
            const float* __restrict__ s, const float* __restrict__ b,
            unsigned short* __restrict__ f_pc)
{
    __shared__ unsigned short wT[32 * 40];
    __shared__ float sS[32], sB[32];
    const int tid = threadIdx.x;
    for (int t = tid; t < 1024; t += 256) {
        int c = t >> 5, d = t & 31;
        wT[d * 40 + c] = f2bf(w[t]);
    }
    if (tid < 32) { sS[tid] = s[tid]; sB[tid] = b[tid]; }
    __syncthreads();
    const int lid = tid & 63, wv = tid >> 6;
    const int col = lid & 15, quad = lid >> 4;
    bf16x8 B0 = *(const bf16x8*)&wT[col * 40 + quad * 8];
    bf16x8 B1 = *(const bf16x8*)&wT[(16 + col) * 40 + quad * 8];
    float s0 = sS[col], b0 = sB[col], s1 = sS[16 + col], b1 = sB[16 + col];
    for (int itp = 0; itp < 4; itp++) {
        const int p0 = blockIdx.x * 256 + wv * 64 + itp * 16;
        const float* fr = &feature[(size_t)(p0 + col) * 32 + quad * 8];
        float4 u0 = *(const float4*)fr;
        float4 u1 = *(const float4*)(fr + 4);
        bf16x8 a = pack8(u0.x, u0.y, u0.z, u0.w, u1.x, u1.y, u1.z, u1.w);
        f32x4 z = {0.f, 0.f, 0.f, 0.f};
        f32x4 d0 = mfma16(a, B0, z);
        f32x4 d1 = mfma16(a, B1, z);
        #pragma unroll
        for (int r = 0; r < 4; r++) {
            int p = p0 + quad * 4 + r;
            f_pc[(size_t)p * 32 + col]      = f2bf(fmaxf(d0[r] * s0 + b0, 0.f));
            f_pc[(size_t)p * 32 + 16 + col] = f2bf(fmaxf(d1[r] * s1 + b1, 0.f));
        }
    }
}

// ---------------------------------------------------------------- attention kernels
// One wave = 16 points (1 point per iter), wave-private LDS, no block barriers in loop.
// lfa/att-mlp B-matrices column-interleaved: B_even col j -> out-channel 2j,
// B_odd col j -> 2j+1, so epilogues write adjacent-channel pairs as one b32.
// Channel storage positions remain identity (no downstream remap needed).
template<int NOUT, bool HAS_LFA2>
__global__ __launch_bounds__(256, 4)
void k_att(const float* __restrict__ xyz, const int* __restrict__ nidx,
           const unsigned short* __restrict__ src,
           const float* __restrict__ wlfa1, const float* __restrict__ slfa1, const float* __restrict__ blfa1,
           const float* __restrict__ wlfa2, const float* __restrict__ slfa2, const float* __restrict__ blfa2,
           const float* __restrict__ wfc,
           const float* __restrict__ wmlp, const float* __restrict__ smlp, const float* __restrict__ bmlp,
           unsigned short* __restrict__ out)
{
    constexpr int NP = NOUT / 32;    // output tile-pairs (32 ch each)
    __shared__ unsigned short wfcT[64 * 72];
    __shared__ unsigned short wl1T[32 * 40];
    __shared__ unsigned short wl2T[HAS_LFA2 ? 32 * 40 : 8];
    __shared__ unsigned short wmT[NOUT * 72];
    __shared__ float sl1[32], bl1[32], sl2[32], bl2[32], sml[NOUT], bml[NOUT];
    __shared__ unsigned short fcat[4][16 * 72];   // [wave][nbr*72 + pos]
    __shared__ unsigned short aggL[4][4 * 72];    // [wave][ptmod4*72 + pos]

    const int tid = threadIdx.x;
    // ---- stage weights
    for (int t = tid; t < 64 * 64; t += 256) {    // wfcT[d][k] = wfc[k][d], K identity
        int c = t >> 6, d = t & 63;
        wfcT[d * 72 + c] = f2bf(wfc[t]);
    }
    for (int t = tid; t < 32 * 32; t += 256) {    // lfa weights, output-interleaved slots
        int k = t >> 5, d = t & 31;
        int slot = (d & 1) * 16 + (d >> 1);       // even ch -> rows 0..15, odd -> 16..31
        wl1T[slot * 40 + k] = f2bf(k < 10 ? wlfa1[k * 32 + d] : 0.f);
        if (HAS_LFA2) wl2T[slot * 40 + k] = f2bf(wlfa2[k * 32 + d]);
    }
    for (int t = tid; t < 64 * NOUT; t += 256) {  // att-mlp, output-interleaved within 32-ch pairs
        int c = t / NOUT, d = t % NOUT;
        int slot = (d >> 5) * 32 + (d & 1) * 16 + ((d & 31) >> 1);
        wmT[slot * 72 + c] = f2bf(wmlp[t]);
    }
    if (tid < 32) {
        sl1[tid] = slfa1[tid]; bl1[tid] = blfa1[tid];
        if (HAS_LFA2) { sl2[tid] = slfa2[tid]; bl2[tid] = blfa2[tid]; }
    }
    if (tid < NOUT) { sml[tid] = smlp[tid]; bml[tid] = bmlp[tid]; }
    __syncthreads();

    const int lid = tid & 63, wv = tid >> 6;
    const int col = lid & 15, quad = lid >> 4;

    // ---- preload B-fragments
    bf16x8 Bfc[4][2];
    #pragma unroll
    for (int nt = 0; nt < 4; nt++)
        #pragma unroll
        for (int ks = 0; ks < 2; ks++)
            Bfc[nt][ks] = *(const bf16x8*)&wfcT[(nt * 16 + col) * 72 + ks * 32 + quad * 8];
    bf16x8 Bl1e = *(const bf16x8*)&wl1T[col * 40 + quad * 8];
    bf16x8 Bl1o = *(const bf16x8*)&wl1T[(16 + col) * 40 + quad * 8];
    bf16x8 Bl2e, Bl2o;
    if (HAS_LFA2) {
        Bl2e = *(const bf16x8*)&wl2T[col * 40 + quad * 8];
        Bl2o = *(const bf16x8*)&wl2T[(16 + col) * 40 + quad * 8];
    }
    bf16x8 Bme[NP][2], Bmo[NP][2];
    #pragma unroll
    for (int tp = 0; tp < NP; tp++)
        #pragma unroll
        for (int ks = 0; ks < 2; ks++) {
            Bme[tp][ks] = *(const bf16x8*)&wmT[(tp * 32 + col) * 72 + ks * 32 + quad * 8];
            Bmo[tp][ks] = *(const bf16x8*)&wmT[(tp * 32 + 16 + col) * 72 + ks * 32 + quad * 8];
        }

    // hoisted paired scale/bias
    const float sl1e = sl1[2 * col], bl1e = bl1[2 * col], sl1o = sl1[2 * col + 1], bl1o = bl1[2 * col + 1];
    float sl2e = 0.f, bl2e = 0.f, sl2o = 0.f, bl2o = 0.f;
    if (HAS_LFA2) { sl2e = sl2[2 * col]; bl2e = bl2[2 * col]; sl2o = sl2[2 * col + 1]; bl2o = bl2[2 * col + 1]; }
    float sme[NP], bme[NP], smo[NP], bmo[NP];
    #pragma unroll
    for (int tp = 0; tp < NP; tp++) {
        sme[tp] = sml[tp * 32 + 2 * col]; bme[tp] = bml[tp * 32 + 2 * col];
        smo[tp] = sml[tp * 32 + 2 * col + 1]; bmo[tp] = bml[tp * 32 + 2 * col + 1];
    }

    unsigned short* fc = fcat[wv];
    unsigned short* ag = aggL[wv];
    const f32x4 z = {0.f, 0.f, 0.f, 0.f};
    const int pbase = blockIdx.x * 64 + wv * 16;
    const int pb = (pbase / NPTS) * NPTS;

    #pragma unroll 4
    for (int it = 0; it < 16; it++) {
        const int p = pbase + it;

        // ---- gather neighbor features -> fc[:, 0:32]
        {
            const int gk = lid >> 2, gp = lid & 3;
            int j = nidx[p * KNB + gk];
            bf16x8 v = *(const bf16x8*)&src[(size_t)(pb + j) * 32 + gp * 8];
            *(bf16x8*)&fc[gk * 72 + gp * 8] = v;
        }

        // ---- lfa1 (A in registers: rows=nbr, K=rel_pos padded to 32) [+ lfa2]
        {
            float f0 = 0.f, f1 = 0.f, f2 = 0.f, f3 = 0.f, f4 = 0.f, f5 = 0.f, f6 = 0.f, f7 = 0.f;
            if (quad < 2) {
                int j = nidx[p * KNB + col];
                float cx = xyz[p * 3], cy = xyz[p * 3 + 1], cz = xyz[p * 3 + 2];
                float nx = xyz[(pb + j) * 3], ny = xyz[(pb + j) * 3 + 1], nz = xyz[(pb + j) * 3 + 2];
                float rx = cx - nx, ry = cy - ny, rz = cz - nz;
                float dd = sqrtf(rx * rx + ry * ry + rz * rz);
                if (quad == 0) { f0 = dd; f1 = rx; f2 = ry; f3 = rz; f4 = cx; f5 = cy; f6 = cz; f7 = nx; }
                else           { f0 = ny; f1 = nz; }
            }
            bf16x8 a = pack8(f0, f1, f2, f3, f4, f5, f6, f7);
            f32x4 d0 = mfma16(a, Bl1e, z);
            f32x4 d1 = mfma16(a, Bl1o, z);
            #pragma unroll
            for (int r = 0; r < 4; r++) {
                float ye = fmaxf(d0[r] * sl1e + bl1e, 0.f);
                float yo = fmaxf(d1[r] * sl1o + bl1o, 0.f);
                *(unsigned*)&fc[(quad * 4 + r) * 72 + 32 + 2 * col] = pk2(ye, yo);
            }
            if (HAS_LFA2) {
                bf16x8 a2 = *(const bf16x8*)&fc[col * 72 + 32 + quad * 8];
                f32x4 e0 = mfma16(a2, Bl2e, z);
                f32x4 e1 = mfma16(a2, Bl2o, z);
                #pragma unroll
                for (int r = 0; r < 4; r++) {
                    float ye = fmaxf(e0[r] * sl2e + bl2e, 0.f);
                    float yo = fmaxf(e1[r] * sl2o + bl2o, 0.f);
                    *(unsigned*)&fc[(quad * 4 + r) * 72 + 32 + 2 * col] = pk2(ye, yo);
                }
            }
        }

        // ---- logits GEMM + softmax over 16 nbrs + pooled agg
        {
            bf16x8 a0 = *(const bf16x8*)&fc[col * 72 + quad * 8];
            bf16x8 a1 = *(const bf16x8*)&fc[col * 72 + 32 + quad * 8];
            #pragma unroll
            for (int nt = 0; nt < 4; nt++) {
                f32x4 L = mfma16(a1, Bfc[nt][1], mfma16(a0, Bfc[nt][0], z));
                // no max-subtraction: |logit| << 88 (sigma ~3), exp safe in f32
                float e0 = __expf(L[0]), e1 = __expf(L[1]), e2 = __expf(L[2]), e3 = __expf(L[3]);
                float sden = (e0 + e1) + (e2 + e3);
                const unsigned short* frr = &fc[quad * 4 * 72 + nt * 16 + col];
                float av = e0 * bf2f(frr[0]) + e1 * bf2f(frr[72]) + e2 * bf2f(frr[144]) + e3 * bf2f(frr[216]);
                av   += __shfl_xor(av, 16, 64);
                sden += __shfl_xor(sden, 16, 64);
                av   += __shfl_xor(av, 32, 64);
                sden += __shfl_xor(sden, 32, 64);
                if (quad == 0) ag[(it & 3) * 72 + nt * 16 + col] = f2bf(av / sden);
            }
        }

        // ---- att-MLP batched over 4 points every 4th iter
        if ((it & 3) == 3) {
            bf16x8 am0 = *(const bf16x8*)&ag[(col & 3) * 72 + quad * 8];
            bf16x8 am1 = *(const bf16x8*)&ag[(col & 3) * 72 + 32 + quad * 8];
            #pragma unroll
            for (int tp = 0; tp < NP; tp++) {
                f32x4 de = mfma16(am1, Bme[tp][1], mfma16(am0, Bme[tp][0], z));
                f32x4 dd = mfma16(am1, Bmo[tp][1], mfma16(am0, Bmo[tp][0], z));
                if (quad == 0) {
                    #pragma unroll
                    for (int r = 0; r < 4; r++) {   // C rows 0..3 = points p-3..p
                        float ye = fmaxf(de[r] * sme[tp] + bme[tp], 0.f);
                        float yo = fmaxf(dd[r] * smo[tp] + bmo[tp], 0.f);
                        *(unsigned*)&out[(size_t)(p - 3 + r) * NOUT + tp * 32 + 2 * col] = pk2(ye, yo);
                    }
                }
            }
        }
    }
}

// ---------------------------------------------------------------- kernel 4: out = leaky(cb(f_pc2,mlp2) + cb(feature,sc))
__global__ __launch_bounds__(256)
void k_out(const unsigned short* __restrict__ f_pc2, const float* __restrict__ feature,
           const float* __restrict__ w2, const float* __restrict__ s2, const float* __restrict__ b2,
           const float* __restrict__ wsc, const float* __restrict__ ssc, const float* __restrict__ bsc,
           float* __restrict__ out)
{
    __shared__ unsigned short w2T[128 * 72];
    __shared__ unsigned short wsT[128 * 40];
    __shared__ float sA[128], sB2[128], sC[128];
    const int tid = threadIdx.x;
    for (int t = tid; t < 64 * 128; t += 256) {
        int c = t >> 7, d = t & 127;
        w2T[d * 72 + c] = f2bf(w2[t]);
    }
    for (int t = tid; t < 32 * 128; t += 256) {
        int c = t >> 7, d = t & 127;
        wsT[d * 40 + c] = f2bf(wsc[t]);
    }
    if (tid < 128) { sA[tid] = s2[tid]; sB2[tid] = ssc[tid]; sC[tid] = b2[tid] + bsc[tid]; }
    __syncthreads();
    const int lid = tid & 63, wv = tid >> 6;
    const int col = lid & 15, quad = lid >> 4;
    const f32x4 z = {0.f, 0.f, 0.f, 0.f};
    for (int itp = 0; itp < 2; itp++) {
        const int p0 = blockIdx.x * 128 + wv * 32 + itp * 16;
        const unsigned short* ar = &f_pc2[(size_t)(p0 + col) * 64 + quad * 8];
        bf16x8 a10 = *(const bf16x8*)ar;
        bf16x8 a11 = *(const bf16x8*)(ar + 32);
        const float* fr = &feature[(size_t)(p0 + col) * 32 + quad * 8];
        float4 u0 = *(const float4*)fr;
        float4 u1 = *(const float4*)(fr + 4);
        bf16x8 a2 = pack8(u0.x, u0.y, u0.z, u0.w, u1.x, u1.y, u1.z, u1.w);
        #pragma unroll
        for (int nt = 0; nt < 8; nt++) {
            bf16x8 bk0 = *(const bf16x8*)&w2T[(nt * 16 + col) * 72 + quad * 8];
            bf16x8 bk1 = *(const bf16x8*)&w2T[(nt * 16 + col) * 72 + 32 + quad * 8];
            bf16x8 bs  = *(const bf16x8*)&wsT[(nt * 16 + col) * 40 + quad * 8];
            f32x4 d = mfma16(a11, bk1, mfma16(a10, bk0, z));
            f32x4 e = mfma16(a2, bs, z);
            int n = nt * 16 + col;
            float ss = sA[n], st = sB2[n], bb = sC[n];
            #pragma unroll
            for (int r = 0; r < 4; r++) {
                float y = d[r] * ss + e[r] * st + bb;
                y = y > 0.f ? y : 0.2f * y;
                out[(size_t)(p0 + quad * 4 + r) * 128 + n] = y;
            }
        }
    }
}

// ---------------------------------------------------------------- launch
extern "C" void kernel_launch(void* const* d_in, const int* in_sizes, int n_in,
                              void* d_out, int out_size, void* d_ws, size_t ws_size,
                              hipStream_t stream) {
    const float* feature = (const float*)d_in[0];
    const float* xyz     = (const float*)d_in[1];
    const int*   nidx    = (const int*)d_in[2];
    const float* w_mlp1 = (const float*)d_in[3];
    const float* s_mlp1 = (const float*)d_in[4];
    const float* b_mlp1 = (const float*)d_in[5];
    const float* w_lfa1 = (const float*)d_in[6];
    const float* s_lfa1 = (const float*)d_in[7];
    const float* b_lfa1 = (const float*)d_in[8];
    const float* w_att1_fc  = (const float*)d_in[9];
    const float* w_att1_mlp = (const float*)d_in[10];
    const float* s_att1_mlp = (const float*)d_in[11];
    const float* b_att1_mlp = (const float*)d_in[12];
    const float* w_lfa2 = (const float*)d_in[13];
    const float* s_lfa2 = (const float*)d_in[14];
    const float* b_lfa2 = (const float*)d_in[15];
    const float* w_att2_fc  = (const float*)d_in[16];
    const float* w_att2_mlp = (const float*)d_in[17];
    const float* s_att2_mlp = (const float*)d_in[18];
    const float* b_att2_mlp = (const float*)d_in[19];
    const float* w_mlp2 = (const float*)d_in[20];
    const float* s_mlp2 = (const float*)d_in[21];
    const float* b_mlp2 = (const float*)d_in[22];
    const float* w_sc = (const float*)d_in[23];
    const float* s_sc = (const float*)d_in[24];
    const float* b_sc = (const float*)d_in[25];

    unsigned short* f_pc  = (unsigned short*)d_ws;               // [BNPTS][32] bf16
    unsigned short* f_agg = f_pc  + (size_t)BNPTS * 32;          // [BNPTS][32] bf16
    unsigned short* f_pc2 = f_agg + (size_t)BNPTS * 32;          // [BNPTS][64] bf16
    float* out = (float*)d_out;

    k_mlp1<<<BNPTS / 256, 256, 0, stream>>>(feature, w_mlp1, s_mlp1, b_mlp1, f_pc);
    k_att<32, false><<<BNPTS / 64, 256, 0, stream>>>(
        xyz, nidx, f_pc,
        w_lfa1, s_lfa1, b_lfa1,
        w_lfa1, s_lfa1, b_lfa1,              // lfa2 slots unused
        w_att1_fc, w_att1_mlp, s_att1_mlp, b_att1_mlp, f_agg);
    k_att<64, true><<<BNPTS / 64, 256, 0, stream>>>(
        xyz, nidx, f_agg,
        w_lfa1, s_lfa1, b_lfa1,
        w_lfa2, s_lfa2, b_lfa2,
        w_att2_fc, w_att2_mlp, s_att2_mlp, b_att2_mlp, f_pc2);
    k_out<<<BNPTS / 128, 256, 0, stream>>>(
        f_pc2, feature,
        w_mlp2, s_mlp2, b_mlp2,
        w_sc, s_sc, b_sc, out);
}

// Round 5
// 448.077 us; speedup vs baseline: 4.5882x; 1.0164x over previous
//
#include <hip/hip_runtime.h>
#include <hip/hip_bf16.h>

#define NPTS  40960
#define BNPTS 163840   // 4 batches x 40960
#define KNB   16

using bf16x8 = __attribute__((ext_vector_type(8))) short;
using f32x4  = __attribute__((ext_vector_type(4))) float;

__device__ __forceinline__ unsigned short f2bf(float x) {
    union { float f; unsigned u; } v; v.f = x;
    unsigned r = v.u + 0x7fffu + ((v.u >> 16) & 1u);   // RTNE
    return (unsigned short)(r >> 16);
}
__device__ __forceinline__ float bf2f(unsigned short u) {
    union { unsigned u; float f; } v; v.u = ((unsigned)u) << 16;
    return v.f;
}
// pack two floats -> packed bf16x2 (lo at low half) via v_cvt_pk_bf16_f32
__device__ __forceinline__ unsigned pk2(float lo, float hi) {
    union { __hip_bfloat162 h; unsigned u; } v;
    v.h = __float22bfloat162_rn(float2{lo, hi});
    return v.u;
}
__device__ __forceinline__ bf16x8 pack8(float a0, float a1, float a2, float a3,
                                        float a4, float a5, float a6, float a7) {
    union { unsigned u[4]; bf16x8 v; } w;
    w.u[0] = pk2(a0, a1); w.u[1] = pk2(a2, a3);
    w.u[2] = pk2(a4, a5); w.u[3] = pk2(a6, a7);
    return w.v;
}
__device__ __forceinline__ f32x4 mfma16(bf16x8 a, bf16x8 b, f32x4 c) {
    return __builtin_amdgcn_mfma_f32_16x16x32_bf16(a, b, c, 0, 0, 0);
}

// ---------------------------------------------------------------- kernel 1: f_pc = cb(feature, mlp1) -> bf16 [pts][32]
__global__ __launch_bounds__(256)
void k_mlp1(const float* __restrict__ feature, const float* __restrict__ w,
            const float* __restrict__ s, const float* __restrict__ b,
            unsigned short* __restrict__ f_pc)
{
    __shared__ unsigned short wT[32 * 40];
    __shared__ float sS[32], sB[32];
    const int tid = threadIdx.x;
    for (int t = tid; t < 1024; t += 256) {
        int c = t >> 5, d = t & 31;
        wT[d * 40 + c] = f2bf(w[t]);
    }
    if (tid < 32) { sS[tid] = s[tid]; sB[tid] = b[tid]; }
    __syncthreads();
    const int lid = tid & 63, wv = tid >> 6;
    const int col = lid & 15, quad = lid >> 4;
    bf16x8 B0 = *(const bf16x8*)&wT[col * 40 + quad * 8];
    bf16x8 B1 = *(const bf16x8*)&wT[(16 + col) * 40 + quad * 8];
    float s0 = sS[col], b0 = sB[col], s1 = sS[16 + col], b1 = sB[16 + col];
    for (int itp = 0; itp < 4; itp++) {
        const int p0 = blockIdx.x * 256 + wv * 64 + itp * 16;
        const float* fr = &feature[(size_t)(p0 + col) * 32 + quad * 8];
        float4 u0 = *(const float4*)fr;
        float4 u1 = *(const float4*)(fr + 4);
        bf16x8 a = pack8(u0.x, u0.y, u0.z, u0.w, u1.x, u1.y, u1.z, u1.w);
        f32x4 z = {0.f, 0.f, 0.f, 0.f};
        f32x4 d0 = mfma16(a, B0, z);
        f32x4 d1 = mfma16(a, B1, z);
        #pragma unroll
        for (int r = 0; r < 4; r++) {
            int p = p0 + quad * 4 + r;
            f_pc[(size_t)p * 32 + col]      = f2bf(fmaxf(d0[r] * s0 + b0, 0.f));
            f_pc[(size_t)p * 32 + 16 + col] = f2bf(fmaxf(d1[r] * s1 + b1, 0.f));
        }
    }
}

// ---------------------------------------------------------------- attention kernels
// One wave = 16 points (1 point per iter), wave-private LDS, no block barriers in loop.
// XCD swizzle: blocks dispatch round-robin over 8 XCDs; remap so each XCD works a
// contiguous 20480-point window (half a batch) -> gather working set (2.6 MB src
// slice) stays resident in that XCD's 4 MB L2.
// lfa/att-mlp B-matrices column-interleaved: epilogues write channel pairs as one b32.
template<int NOUT, bool HAS_LFA2>
__global__ __launch_bounds__(256, 3)   // allow up to ~170 VGPR: keep B-fragments live
void k_att(const float* __restrict__ xyz, const int* __restrict__ nidx,
           const unsigned short* __restrict__ src,
           const float* __restrict__ wlfa1, const float* __restrict__ slfa1, const float* __restrict__ blfa1,
           const float* __restrict__ wlfa2, const float* __restrict__ slfa2, const float* __restrict__ blfa2,
           const float* __restrict__ wfc,
           const float* __restrict__ wmlp, const float* __restrict__ smlp, const float* __restrict__ bmlp,
           unsigned short* __restrict__ out)
{
    constexpr int NP = NOUT / 32;    // output tile-pairs (32 ch each)
    __shared__ unsigned short wfcT[64 * 72];
    __shared__ unsigned short wl1T[32 * 40];
    __shared__ unsigned short wl2T[HAS_LFA2 ? 32 * 40 : 8];
    __shared__ unsigned short wmT[NOUT * 72];
    __shared__ float sl1[32], bl1[32], sl2[32], bl2[32], sml[NOUT], bml[NOUT];
    __shared__ unsigned short fcat[4][16 * 72];   // [wave][nbr*72 + pos]
    __shared__ unsigned short aggL[4][4 * 72];    // [wave][ptmod4*72 + pos]

    const int tid = threadIdx.x;
    // ---- stage weights
    for (int t = tid; t < 64 * 64; t += 256) {    // wfcT[d][k] = wfc[k][d], K identity
        int c = t >> 6, d = t & 63;
        wfcT[d * 72 + c] = f2bf(wfc[t]);
    }
    for (int t = tid; t < 32 * 32; t += 256) {    // lfa weights, output-interleaved slots
        int k = t >> 5, d = t & 31;
        int slot = (d & 1) * 16 + (d >> 1);       // even ch -> rows 0..15, odd -> 16..31
        wl1T[slot * 40 + k] = f2bf(k < 10 ? wlfa1[k * 32 + d] : 0.f);
        if (HAS_LFA2) wl2T[slot * 40 + k] = f2bf(wlfa2[k * 32 + d]);
    }
    for (int t = tid; t < 64 * NOUT; t += 256) {  // att-mlp, output-interleaved within 32-ch pairs
        int c = t / NOUT, d = t % NOUT;
        int slot = (d >> 5) * 32 + (d & 1) * 16 + ((d & 31) >> 1);
        wmT[slot * 72 + c] = f2bf(wmlp[t]);
    }
    if (tid < 32) {
        sl1[tid] = slfa1[tid]; bl1[tid] = blfa1[tid];
        if (HAS_LFA2) { sl2[tid] = slfa2[tid]; bl2[tid] = blfa2[tid]; }
    }
    if (tid < NOUT) { sml[tid] = smlp[tid]; bml[tid] = bmlp[tid]; }
    __syncthreads();

    const int lid = tid & 63, wv = tid >> 6;
    const int col = lid & 15, quad = lid >> 4;

    // ---- preload B-fragments
    bf16x8 Bfc[4][2];
    #pragma unroll
    for (int nt = 0; nt < 4; nt++)
        #pragma unroll
        for (int ks = 0; ks < 2; ks++)
            Bfc[nt][ks] = *(const bf16x8*)&wfcT[(nt * 16 + col) * 72 + ks * 32 + quad * 8];
    bf16x8 Bl1e = *(const bf16x8*)&wl1T[col * 40 + quad * 8];
    bf16x8 Bl1o = *(const bf16x8*)&wl1T[(16 + col) * 40 + quad * 8];
    bf16x8 Bl2e, Bl2o;
    if (HAS_LFA2) {
        Bl2e = *(const bf16x8*)&wl2T[col * 40 + quad * 8];
        Bl2o = *(const bf16x8*)&wl2T[(16 + col) * 40 + quad * 8];
    }
    bf16x8 Bme[NP][2], Bmo[NP][2];
    #pragma unroll
    for (int tp = 0; tp < NP; tp++)
        #pragma unroll
        for (int ks = 0; ks < 2; ks++) {
            Bme[tp][ks] = *(const bf16x8*)&wmT[(tp * 32 + col) * 72 + ks * 32 + quad * 8];
            Bmo[tp][ks] = *(const bf16x8*)&wmT[(tp * 32 + 16 + col) * 72 + ks * 32 + quad * 8];
        }

    // hoisted paired scale/bias
    const float sl1e = sl1[2 * col], bl1e = bl1[2 * col], sl1o = sl1[2 * col + 1], bl1o = bl1[2 * col + 1];
    float sl2e = 0.f, bl2e = 0.f, sl2o = 0.f, bl2o = 0.f;
    if (HAS_LFA2) { sl2e = sl2[2 * col]; bl2e = bl2[2 * col]; sl2o = sl2[2 * col + 1]; bl2o = bl2[2 * col + 1]; }
    float sme[NP], bme[NP], smo[NP], bmo[NP];
    #pragma unroll
    for (int tp = 0; tp < NP; tp++) {
        sme[tp] = sml[tp * 32 + 2 * col]; bme[tp] = bml[tp * 32 + 2 * col];
        smo[tp] = sml[tp * 32 + 2 * col + 1]; bmo[tp] = bml[tp * 32 + 2 * col + 1];
    }

    unsigned short* fc = fcat[wv];
    unsigned short* ag = aggL[wv];
    const f32x4 z = {0.f, 0.f, 0.f, 0.f};
    // XCD swizzle: grid = 2560 = 8 XCDs x 320; XCD i (blk%8==i) -> contiguous window
    const int blk = (int)blockIdx.x;
    const int vblk = (blk & 7) * 320 + (blk >> 3);
    const int pbase = vblk * 64 + wv * 16;
    const int pb = (pbase / NPTS) * NPTS;

    #pragma unroll 1
    for (int it = 0; it < 16; it++) {
        const int p = pbase + it;

        // ---- gather neighbor features -> fc[:, 0:32]
        {
            const int gk = lid >> 2, gp = lid & 3;
            int j = nidx[p * KNB + gk];
            bf16x8 v = *(const bf16x8*)&src[(size_t)(pb + j) * 32 + gp * 8];
            *(bf16x8*)&fc[gk * 72 + gp * 8] = v;
        }

        // ---- lfa1 (A in registers: rows=nbr, K=rel_pos padded to 32) [+ lfa2]
        {
            float f0 = 0.f, f1 = 0.f, f2 = 0.f, f3 = 0.f, f4 = 0.f, f5 = 0.f, f6 = 0.f, f7 = 0.f;
            if (quad < 2) {
                int j = nidx[p * KNB + col];
                float cx = xyz[p * 3], cy = xyz[p * 3 + 1], cz = xyz[p * 3 + 2];
                float nx = xyz[(pb + j) * 3], ny = xyz[(pb + j) * 3 + 1], nz = xyz[(pb + j) * 3 + 2];
                float rx = cx - nx, ry = cy - ny, rz = cz - nz;
                float dd = sqrtf(rx * rx + ry * ry + rz * rz);
                if (quad == 0) { f0 = dd; f1 = rx; f2 = ry; f3 = rz; f4 = cx; f5 = cy; f6 = cz; f7 = nx; }
                else           { f0 = ny; f1 = nz; }
            }
            bf16x8 a = pack8(f0, f1, f2, f3, f4, f5, f6, f7);
            f32x4 d0 = mfma16(a, Bl1e, z);
            f32x4 d1 = mfma16(a, Bl1o, z);
            #pragma unroll
            for (int r = 0; r < 4; r++) {
                float ye = fmaxf(d0[r] * sl1e + bl1e, 0.f);
                float yo = fmaxf(d1[r] * sl1o + bl1o, 0.f);
                *(unsigned*)&fc[(quad * 4 + r) * 72 + 32 + 2 * col] = pk2(ye, yo);
            }
            if (HAS_LFA2) {
                bf16x8 a2 = *(const bf16x8*)&fc[col * 72 + 32 + quad * 8];
                f32x4 e0 = mfma16(a2, Bl2e, z);
                f32x4 e1 = mfma16(a2, Bl2o, z);
                #pragma unroll
                for (int r = 0; r < 4; r++) {
                    float ye = fmaxf(e0[r] * sl2e + bl2e, 0.f);
                    float yo = fmaxf(e1[r] * sl2o + bl2o, 0.f);
                    *(unsigned*)&fc[(quad * 4 + r) * 72 + 32 + 2 * col] = pk2(ye, yo);
                }
            }
        }

        // ---- logits GEMM + softmax over 16 nbrs + pooled agg
        {
            bf16x8 a0 = *(const bf16x8*)&fc[col * 72 + quad * 8];
            bf16x8 a1 = *(const bf16x8*)&fc[col * 72 + 32 + quad * 8];
            #pragma unroll
            for (int nt = 0; nt < 4; nt++) {
                f32x4 L = mfma16(a1, Bfc[nt][1], mfma16(a0, Bfc[nt][0], z));
                // no max-subtraction: |logit| << 88 (sigma ~3), exp safe in f32
                float e0 = __expf(L[0]), e1 = __expf(L[1]), e2 = __expf(L[2]), e3 = __expf(L[3]);
                float sden = (e0 + e1) + (e2 + e3);
                const unsigned short* frr = &fc[quad * 4 * 72 + nt * 16 + col];
                float av = e0 * bf2f(frr[0]) + e1 * bf2f(frr[72]) + e2 * bf2f(frr[144]) + e3 * bf2f(frr[216]);
                av   += __shfl_xor(av, 16, 64);
                sden += __shfl_xor(sden, 16, 64);
                av   += __shfl_xor(av, 32, 64);
                sden += __shfl_xor(sden, 32, 64);
                if (quad == 0) ag[(it & 3) * 72 + nt * 16 + col] = f2bf(av / sden);
            }
        }

        // ---- att-MLP batched over 4 points every 4th iter
        if ((it & 3) == 3) {
            bf16x8 am0 = *(const bf16x8*)&ag[(col & 3) * 72 + quad * 8];
            bf16x8 am1 = *(const bf16x8*)&ag[(col & 3) * 72 + 32 + quad * 8];
            #pragma unroll
            for (int tp = 0; tp < NP; tp++) {
                f32x4 de = mfma16(am1, Bme[tp][1], mfma16(am0, Bme[tp][0], z));
                f32x4 dd = mfma16(am1, Bmo[tp][1], mfma16(am0, Bmo[tp][0], z));
                if (quad == 0) {
                    #pragma unroll
                    for (int r = 0; r < 4; r++) {   // C rows 0..3 = points p-3..p
                        float ye = fmaxf(de[r] * sme[tp] + bme[tp], 0.f);
                        float yo = fmaxf(dd[r] * smo[tp] + bmo[tp], 0.f);
                        *(unsigned*)&out[(size_t)(p - 3 + r) * NOUT + tp * 32 + 2 * col] = pk2(ye, yo);
                    }
                }
            }
        }
    }
}

// ---------------------------------------------------------------- kernel 4: out = leaky(cb(f_pc2,mlp2) + cb(feature,sc))
__global__ __launch_bounds__(256)
void k_out(const unsigned short* __restrict__ f_pc2, const float* __restrict__ feature,
           const float* __restrict__ w2, const float* __restrict__ s2, const float* __restrict__ b2,
           const float* __restrict__ wsc, const float* __restrict__ ssc, const float* __restrict__ bsc,
           float* __restrict__ out)
{
    __shared__ unsigned short w2T[128 * 72];
    __shared__ unsigned short wsT[128 * 40];
    __shared__ float sA[128], sB2[128], sC[128];
    const int tid = threadIdx.x;
    for (int t = tid; t < 64 * 128; t += 256) {
        int c = t >> 7, d = t & 127;
        w2T[d * 72 + c] = f2bf(w2[t]);
    }
    for (int t = tid; t < 32 * 128; t += 256) {
        int c = t >> 7, d = t & 127;
        wsT[d * 40 + c] = f2bf(wsc[t]);
    }
    if (tid < 128) { sA[tid] = s2[tid]; sB2[tid] = ssc[tid]; sC[tid] = b2[tid] + bsc[tid]; }
    __syncthreads();
    const int lid = tid & 63, wv = tid >> 6;
    const int col = lid & 15, quad = lid >> 4;
    const f32x4 z = {0.f, 0.f, 0.f, 0.f};
    for (int itp = 0; itp < 2; itp++) {
        const int p0 = blockIdx.x * 128 + wv * 32 + itp * 16;
        const unsigned short* ar = &f_pc2[(size_t)(p0 + col) * 64 + quad * 8];
        bf16x8 a10 = *(const bf16x8*)ar;
        bf16x8 a11 = *(const bf16x8*)(ar + 32);
        const float* fr = &feature[(size_t)(p0 + col) * 32 + quad * 8];
        float4 u0 = *(const float4*)fr;
        float4 u1 = *(const float4*)(fr + 4);
        bf16x8 a2 = pack8(u0.x, u0.y, u0.z, u0.w, u1.x, u1.y, u1.z, u1.w);
        #pragma unroll
        for (int nt = 0; nt < 8; nt++) {
            bf16x8 bk0 = *(const bf16x8*)&w2T[(nt * 16 + col) * 72 + quad * 8];
            bf16x8 bk1 = *(const bf16x8*)&w2T[(nt * 16 + col) * 72 + 32 + quad * 8];
            bf16x8 bs  = *(const bf16x8*)&wsT[(nt * 16 + col) * 40 + quad * 8];
            f32x4 d = mfma16(a11, bk1, mfma16(a10, bk0, z));
            f32x4 e = mfma16(a2, bs, z);
            int n = nt * 16 + col;
            float ss = sA[n], st = sB2[n], bb = sC[n];
            #pragma unroll
            for (int r = 0; r < 4; r++) {
                float y = d[r] * ss + e[r] * st + bb;
                y = y > 0.f ? y : 0.2f * y;
                out[(size_t)(p0 + quad * 4 + r) * 128 + n] = y;
            }
        }
    }
}

// ---------------------------------------------------------------- launch
extern "C" void kernel_launch(void* const* d_in, const int* in_sizes, int n_in,
                              void* d_out, int out_size, void* d_ws, size_t ws_size,
                              hipStream_t stream) {
    const float* feature = (const float*)d_in[0];
    const float* xyz     = (const float*)d_in[1];
    const int*   nidx    = (const int*)d_in[2];
    const float* w_mlp1 = (const float*)d_in[3];
    const float* s_mlp1 = (const float*)d_in[4];
    const float* b_mlp1 = (const float*)d_in[5];
    const float* w_lfa1 = (const float*)d_in[6];
    const float* s_lfa1 = (const float*)d_in[7];
    const float* b_lfa1 = (const float*)d_in[8];
    const float* w_att1_fc  = (const float*)d_in[9];
    const float* w_att1_mlp = (const float*)d_in[10];
    const float* s_att1_mlp = (const float*)d_in[11];
    const float* b_att1_mlp = (const float*)d_in[12];
    const float* w_lfa2 = (const float*)d_in[13];
    const float* s_lfa2 = (const float*)d_in[14];
    const float* b_lfa2 = (const float*)d_in[15];
    const float* w_att2_fc  = (const float*)d_in[16];
    const float* w_att2_mlp = (const float*)d_in[17];
    const float* s_att2_mlp = (const float*)d_in[18];
    const float* b_att2_mlp = (const float*)d_in[19];
    const float* w_mlp2 = (const float*)d_in[20];
    const float* s_mlp2 = (const float*)d_in[21];
    const float* b_mlp2 = (const float*)d_in[22];
    const float* w_sc = (const float*)d_in[23];
    const float* s_sc = (const float*)d_in[24];
    const float* b_sc = (const float*)d_in[25];

    unsigned short* f_pc  = (unsigned short*)d_ws;               // [BNPTS][32] bf16
    unsigned short* f_agg = f_pc  + (size_t)BNPTS * 32;          // [BNPTS][32] bf16
    unsigned short* f_pc2 = f_agg + (size_t)BNPTS * 32;          // [BNPTS][64] bf16
    float* out = (float*)d_out;

    k_mlp1<<<BNPTS / 256, 256, 0, stream>>>(feature, w_mlp1, s_mlp1, b_mlp1, f_pc);
    k_att<32, false><<<BNPTS / 64, 256, 0, stream>>>(
        xyz, nidx, f_pc,
        w_lfa1, s_lfa1, b_lfa1,
        w_lfa1, s_lfa1, b_lfa1,              // lfa2 slots unused
        w_att1_fc, w_att1_mlp, s_att1_mlp, b_att1_mlp, f_agg);
    k_att<64, true><<<BNPTS / 64, 256, 0, stream>>>(
        xyz, nidx, f_agg,
        w_lfa1, s_lfa1, b_lfa1,
        w_lfa2, s_lfa2, b_lfa2,
        w_att2_fc, w_att2_mlp, s_att2_mlp, b_att2_mlp, f_pc2);
    k_out<<<BNPTS / 128, 256, 0, stream>>>(
        f_pc2, feature,
        w_mlp2, s_mlp2, b_mlp2,
        w_sc, s_sc, b_sc, out);
}